// Round 1
// baseline (832.720 us; speedup 1.0000x reference)
//
#include <hip/hip_runtime.h>

#define B_ 8
#define T_ 1024
#define C_ 1024
#define H_ 16
#define D_ 64
#define TI_ 256
#define FF_ 4096
#define BT_ (B_*T_)
#define BTI_ (B_*TI_)

typedef __bf16 bf16x8 __attribute__((ext_vector_type(8)));
typedef float f32x4 __attribute__((ext_vector_type(4)));

__device__ __forceinline__ unsigned short f2bf(float f){
  unsigned u = __float_as_uint(f);
  u += 0x7fffu + ((u>>16)&1u);
  return (unsigned short)(u>>16);
}

// async global->LDS, 16B per lane; LDS dest = wave-uniform base + lane*16
__device__ __forceinline__ void cp16(const void* g, void* l){
  __builtin_amdgcn_global_load_lds(
      (const __attribute__((address_space(1))) unsigned int*)(unsigned long long)g,
      (__attribute__((address_space(3))) unsigned int*)(unsigned long long)l,
      16, 0, 0);
}

// ---------------------------------------------------------------------------
// GEMM: C[M,N] = A[M,K](bf16) @ Bt[N,K]^T(bf16) + bias, fused epilogue.
// mode 0: out bf16 = v+bias ; mode 1: out bf16 = gelu(v+bias)
// mode 2: out f32 = resid + v + bias
// 128x128 tile, BK=64, XOR-swizzled LDS (chunk c' = c ^ (row&7)).
// ---------------------------------------------------------------------------
__global__ __launch_bounds__(256) void gemm_bt(
    const unsigned short* __restrict__ A,
    const unsigned short* __restrict__ Bt,
    const float* __restrict__ bias,
    const float* __restrict__ resid,
    void* __restrict__ outp,
    int M, int N, int K, int mode)
{
  __shared__ unsigned short sA[128*64];
  __shared__ unsigned short sB[128*64];
  const int tid  = threadIdx.x;
  const int wid  = tid >> 6;
  const int lane = tid & 63;
  const int quad = lane >> 4;
  const int l16  = lane & 15;
  const int row0 = blockIdx.y * 128;
  const int col0 = blockIdx.x * 128;
  const int wr = (wid >> 1) * 64;
  const int wc = (wid & 1) * 64;

  f32x4 zero = {0.f,0.f,0.f,0.f};
  f32x4 acc[4][4];
#pragma unroll
  for (int i=0;i<4;i++)
#pragma unroll
    for (int j=0;j<4;j++) acc[i][j] = zero;

  for (int k0 = 0; k0 < K; k0 += 64){
    if (k0) __syncthreads();
#pragma unroll
    for (int r=0;r<8;r++){
      int chunk = wid*8 + r;          // 0..31 ; <16 => A-tile, else B-tile
      int cA = chunk & 15;
      int slot = cA*64 + lane;        // 16B slot within tile
      int row = slot >> 3;
      int cc = (slot & 7) ^ (row & 7);
      if (chunk < 16)
        cp16(A  + (size_t)(row0+row)*K + (k0 + cc*8), sA + cA*512);
      else
        cp16(Bt + (size_t)(col0+row)*K + (k0 + cc*8), sB + cA*512);
    }
    __syncthreads();
    const char* sAb = (const char*)sA;
    const char* sBb = (const char*)sB;
#pragma unroll
    for (int kk=0;kk<2;kk++){
      bf16x8 af[4], bfb[4];
#pragma unroll
      for (int i=0;i<4;i++){
        int rr = wr + i*16 + l16;
        af[i] = *(const bf16x8*)(sAb + rr*128 + (((kk*4+quad) ^ (rr&7))<<4));
      }
#pragma unroll
      for (int j=0;j<4;j++){
        int rr = wc + j*16 + l16;
        bfb[j] = *(const bf16x8*)(sBb + rr*128 + (((kk*4+quad) ^ (rr&7))<<4));
      }
#pragma unroll
      for (int i=0;i<4;i++)
#pragma unroll
        for (int j=0;j<4;j++)
          acc[i][j] = __builtin_amdgcn_mfma_f32_16x16x32_bf16(af[i], bfb[j], acc[i][j], 0, 0, 0);
    }
  }

#pragma unroll
  for (int j=0;j<4;j++){
    int gc = col0 + wc + j*16 + l16;
    float bz = bias[gc];
#pragma unroll
    for (int i=0;i<4;i++){
      int gr0 = row0 + wr + i*16 + quad*4;
#pragma unroll
      for (int r=0;r<4;r++){
        float v = acc[i][j][r] + bz;
        size_t idx = (size_t)(gr0+r)*N + gc;
        if (mode == 0){
          ((unsigned short*)outp)[idx] = f2bf(v);
        } else if (mode == 1){
          float t = tanhf(0.7978845608028654f*(v + 0.044715f*v*v*v));
          ((unsigned short*)outp)[idx] = f2bf(0.5f*v*(1.f+t));
        } else {
          ((float*)outp)[idx] = resid[idx] + v;
        }
      }
    }
  }
}

// ---------------------------------------------------------------------------
// LayerNorm over C=1024, fp32 in -> bf16 out. One block per row.
// ---------------------------------------------------------------------------
__global__ __launch_bounds__(256) void ln_fwd(
    const float* __restrict__ x, const float* __restrict__ g,
    const float* __restrict__ b, unsigned short* __restrict__ out)
{
  int row = blockIdx.x, t = threadIdx.x;
  const float4* xv = (const float4*)(x + (size_t)row*C_);
  float4 v = xv[t];
  float s  = v.x+v.y+v.z+v.w;
  float ss = v.x*v.x + v.y*v.y + v.z*v.z + v.w*v.w;
#pragma unroll
  for (int o=32;o>0;o>>=1){ s += __shfl_down(s,o); ss += __shfl_down(ss,o); }
  __shared__ float red[16];
  int wid = t>>6, lane = t&63;
  if (lane==0){ red[wid]=s; red[8+wid]=ss; }
  __syncthreads();
  if (t==0){
    red[0] = red[0]+red[1]+red[2]+red[3];
    red[8] = red[8]+red[9]+red[10]+red[11];
  }
  __syncthreads();
  float mu  = red[0] * (1.f/C_);
  float var = red[8] * (1.f/C_) - mu*mu;
  float rstd = rsqrtf(var + 1e-5f);
  float4 gv = ((const float4*)g)[t];
  float4 bv = ((const float4*)b)[t];
  ushort4 o;
  o.x = f2bf((v.x-mu)*rstd*gv.x + bv.x);
  o.y = f2bf((v.y-mu)*rstd*gv.y + bv.y);
  o.z = f2bf((v.z-mu)*rstd*gv.z + bv.z);
  o.w = f2bf((v.w-mu)*rstd*gv.w + bv.w);
  ((ushort4*)(out + (size_t)row*C_))[t] = o;
}

// ---------------------------------------------------------------------------
// Weight transpose+convert: W[Kd,Nd] fp32 -> Wt[Nd,Kd] bf16. 32x32 LDS tile.
// ---------------------------------------------------------------------------
__global__ void wconv_t(const float* __restrict__ W, unsigned short* __restrict__ Wt,
                        int Kd, int Nd)
{
  __shared__ float tile[32][33];
  int tx = threadIdx.x, ty = threadIdx.y;   // 32 x 8
  int n0 = blockIdx.x*32, k0 = blockIdx.y*32;
#pragma unroll
  for (int j=0;j<4;j++)
    tile[ty+8*j][tx] = W[(size_t)(k0+ty+8*j)*Nd + (n0+tx)];
  __syncthreads();
#pragma unroll
  for (int j=0;j<4;j++)
    Wt[(size_t)(n0+ty+8*j)*Kd + (k0+tx)] = f2bf(tile[tx][ty+8*j]);
}

__global__ void conv_bf16(const float* __restrict__ X, unsigned short* __restrict__ Y, int n4)
{
  int i = blockIdx.x*256 + threadIdx.x;
  if (i < n4){
    float4 v = ((const float4*)X)[i];
    ushort4 o; o.x=f2bf(v.x); o.y=f2bf(v.y); o.z=f2bf(v.z); o.w=f2bf(v.w);
    ((ushort4*)Y)[i] = o;
  }
}

// ---------------------------------------------------------------------------
// Fused flash attention. Block = (qtile 64 rows, head, batch), 4 waves x 16 q.
// K staged [s][d] swizzled, V staged transposed [d][s] swizzled,
// P round-trips through per-wave LDS (C-layout -> A-layout, per m120).
// ---------------------------------------------------------------------------
__global__ __launch_bounds__(256) void attn_fwd(
    const unsigned short* __restrict__ Q, int ldq,
    const unsigned short* __restrict__ Kp, const unsigned short* __restrict__ Vp, int ldkv,
    int kvT, int Skv, int Tq, int causal,
    unsigned short* __restrict__ Out, int ldo, float scale)
{
  __shared__ unsigned short sK[64*64];
  __shared__ unsigned short sV[64*64];
  __shared__ unsigned short sP[4*16*64];
  const int tid = threadIdx.x;
  const int wid = tid >> 6;
  const int lane = tid & 63;
  const int quad = lane >> 4;
  const int l16 = lane & 15;
  const int qt = blockIdx.x, h = blockIdx.y, b = blockIdx.z;
  const int hoff = h * D_;

  const int qrow = qt*64 + wid*16 + l16;
  const unsigned short* qb = Q + (size_t)(b*Tq + qrow)*ldq + hoff;
  bf16x8 qf[2];
  qf[0] = *(const bf16x8*)(qb + quad*8);
  qf[1] = *(const bf16x8*)(qb + 32 + quad*8);

  f32x4 zero = {0.f,0.f,0.f,0.f};
  f32x4 O[4];
#pragma unroll
  for (int j=0;j<4;j++) O[j] = zero;
  float mrun[4], lrun[4];
#pragma unroll
  for (int r=0;r<4;r++){ mrun[r] = -1e30f; lrun[r] = 0.f; }

  const int nkb = causal ? (qt+1) : ((Skv+63)>>6);
  char* sPw = (char*)sP + wid*2048;

  for (int kb=0; kb<nkb; ++kb){
    if (kb) __syncthreads();
    // stage K (64 keys x 64 d)
#pragma unroll
    for (int ss=0; ss<2; ++ss){
      int slot = tid + ss*256;
      int srow = slot >> 3;
      int cc = (slot & 7) ^ (srow & 7);
      const unsigned short* g = Kp + (size_t)(b*kvT + kb*64 + srow)*ldkv + hoff + cc*8;
      *(uint4*)((char*)sK + slot*16) = *(const uint4*)g;
    }
    // stage V transposed: sV[d][s]
    {
      int s_ = lane;
      int dbase = wid*16;
      const unsigned short* gv = Vp + (size_t)(b*kvT + kb*64 + s_)*ldkv + hoff + dbase;
      unsigned short vals[16];
      *(uint4*)(vals)   = *(const uint4*)(gv);
      *(uint4*)(vals+8) = *(const uint4*)(gv+8);
      int chunk = s_ >> 3;
      int sb = (s_ & 7)*2;
#pragma unroll
      for (int jj=0; jj<16; ++jj){
        int d = dbase + jj;
        *(unsigned short*)((char*)sV + d*128 + ((chunk ^ (d&7))<<4) + sb) = vals[jj];
      }
    }
    __syncthreads();

    // S = Q K^T
    f32x4 sacc[4];
#pragma unroll
    for (int j=0;j<4;j++) sacc[j] = zero;
#pragma unroll
    for (int j=0;j<4;j++){
      int krow = j*16 + l16;
#pragma unroll
      for (int kk=0;kk<2;kk++){
        bf16x8 kf = *(const bf16x8*)((const char*)sK + krow*128 + (((kk*4+quad) ^ (krow&7))<<4));
        sacc[j] = __builtin_amdgcn_mfma_f32_16x16x32_bf16(qf[kk], kf, sacc[j], 0, 0, 0);
      }
    }
    const int qa0 = qt*64 + wid*16 + quad*4;
    float sc[4][4];
#pragma unroll
    for (int j=0;j<4;j++){
      int key = kb*64 + j*16 + l16;
#pragma unroll
      for (int r=0;r<4;r++){
        float v = sacc[j][r] * scale;
        if (causal && key > qa0 + r) v = -1e30f;
        sc[j][r] = v;
      }
    }
    float mnew[4], alpha[4], rs[4];
#pragma unroll
    for (int r=0;r<4;r++){
      float m = fmaxf(fmaxf(sc[0][r], sc[1][r]), fmaxf(sc[2][r], sc[3][r]));
#pragma unroll
      for (int msk=1; msk<16; msk<<=1) m = fmaxf(m, __shfl_xor(m, msk));
      mnew[r] = fmaxf(mrun[r], m);
      alpha[r] = __expf(mrun[r] - mnew[r]);
      mrun[r] = mnew[r];
      rs[r] = 0.f;
    }
#pragma unroll
    for (int j=0;j<4;j++){
#pragma unroll
      for (int r=0;r<4;r++){
        float p = __expf(sc[j][r] - mnew[r]);
        rs[r] += p;
        int prow = quad*4 + r;
        int cole = j*16 + l16;
        *(unsigned short*)(sPw + prow*128 + (((cole>>3) ^ (prow&7))<<4) + (cole&7)*2) = f2bf(p);
      }
    }
#pragma unroll
    for (int r=0;r<4;r++){
#pragma unroll
      for (int msk=1; msk<16; msk<<=1) rs[r] += __shfl_xor(rs[r], msk);
      lrun[r] = lrun[r]*alpha[r] + rs[r];
    }
#pragma unroll
    for (int j=0;j<4;j++){
      O[j][0] *= alpha[0]; O[j][1] *= alpha[1];
      O[j][2] *= alpha[2]; O[j][3] *= alpha[3];
    }
    // O += P V
    bf16x8 pf[2];
#pragma unroll
    for (int kk=0;kk<2;kk++)
      pf[kk] = *(const bf16x8*)(sPw + l16*128 + (((kk*4+quad) ^ (l16&7))<<4));
#pragma unroll
    for (int j=0;j<4;j++){
      int vrow = j*16 + l16;
#pragma unroll
      for (int kk=0;kk<2;kk++){
        bf16x8 vf = *(const bf16x8*)((const char*)sV + vrow*128 + (((kk*4+quad) ^ (vrow&7))<<4));
        O[j] = __builtin_amdgcn_mfma_f32_16x16x32_bf16(pf[kk], vf, O[j], 0, 0, 0);
      }
    }
  }
#pragma unroll
  for (int j=0;j<4;j++){
#pragma unroll
    for (int r=0;r<4;r++){
      int qa = qt*64 + wid*16 + quad*4 + r;
      float o = O[j][r] / lrun[r];
      Out[(size_t)(b*Tq + qa)*ldo + hoff + j*16 + l16] = f2bf(o);
    }
  }
}

// ---------------------------------------------------------------------------
extern "C" void kernel_launch(void* const* d_in, const int* in_sizes, int n_in,
                              void* d_out, int out_size, void* d_ws, size_t ws_size,
                              hipStream_t stream)
{
  const float* x       = (const float*)d_in[0];
  const float* ximg    = (const float*)d_in[1];
  const float* ln1_g   = (const float*)d_in[2];
  const float* ln1_b   = (const float*)d_in[3];
  const float* ln2_g   = (const float*)d_in[4];
  const float* ln2_b   = (const float*)d_in[5];
  const float* W_attn  = (const float*)d_in[6];
  const float* b_attn  = (const float*)d_in[7];
  const float* W_aproj = (const float*)d_in[8];
  const float* b_aproj = (const float*)d_in[9];
  const float* Wq = (const float*)d_in[10];
  const float* bq = (const float*)d_in[11];
  const float* Wk = (const float*)d_in[12];
  const float* bk = (const float*)d_in[13];
  const float* Wv = (const float*)d_in[14];
  const float* bv = (const float*)d_in[15];
  const float* Wcproj  = (const float*)d_in[16];
  const float* bcproj  = (const float*)d_in[17];
  const float* W_fc    = (const float*)d_in[18];
  const float* b_fc    = (const float*)d_in[19];
  const float* W_mproj = (const float*)d_in[20];
  const float* b_mproj = (const float*)d_in[21];

  char* ws = (char*)d_ws;
  unsigned short* wt_attn  = (unsigned short*)(ws + 0);
  unsigned short* wt_aproj = (unsigned short*)(ws + 6291456);
  unsigned short* wt_q     = (unsigned short*)(ws + 8388608);
  unsigned short* wt_k     = (unsigned short*)(ws + 10485760);
  unsigned short* wt_v     = (unsigned short*)(ws + 12582912);
  unsigned short* wt_cproj = (unsigned short*)(ws + 14680064);
  unsigned short* wt_fc    = (unsigned short*)(ws + 16777216);
  unsigned short* wt_mproj = (unsigned short*)(ws + 25165824);
  unsigned short* ximg_bf  = (unsigned short*)(ws + 33554432);
  float*          xcur     = (float*)(ws + 37748736);
  unsigned short* h_bf     = (unsigned short*)(ws + 71303168);
  unsigned short* qkv      = (unsigned short*)(ws + 88080384);
  unsigned short* att_out  = (unsigned short*)(ws + 88080384 + 50331648);
  unsigned short* u_bf     = (unsigned short*)(ws + 88080384);   // aliases qkv+att_out (both dead by then)
  unsigned short* q2 = (unsigned short*)(ws + 155189248);
  unsigned short* k2 = (unsigned short*)(ws + 171966464);
  unsigned short* v2 = (unsigned short*)(ws + 176160768);
  unsigned short* ca = (unsigned short*)(ws + 180355072);

  dim3 tb(32,8);
  wconv_t<<<dim3(96,32),  tb, 0, stream>>>(W_attn,  wt_attn,  1024, 3072);
  wconv_t<<<dim3(32,32),  tb, 0, stream>>>(W_aproj, wt_aproj, 1024, 1024);
  wconv_t<<<dim3(32,32),  tb, 0, stream>>>(Wq,      wt_q,     1024, 1024);
  wconv_t<<<dim3(32,32),  tb, 0, stream>>>(Wk,      wt_k,     1024, 1024);
  wconv_t<<<dim3(32,32),  tb, 0, stream>>>(Wv,      wt_v,     1024, 1024);
  wconv_t<<<dim3(32,32),  tb, 0, stream>>>(Wcproj,  wt_cproj, 1024, 1024);
  wconv_t<<<dim3(128,32), tb, 0, stream>>>(W_fc,    wt_fc,    1024, 4096);
  wconv_t<<<dim3(32,128), tb, 0, stream>>>(W_mproj, wt_mproj, 4096, 1024);
  conv_bf16<<<BTI_*C_/4/256, 256, 0, stream>>>(ximg, ximg_bf, BTI_*C_/4);
  hipMemcpyAsync(xcur, x, (size_t)BT_*C_*4, hipMemcpyDeviceToDevice, stream);

  // self-attention
  ln_fwd<<<BT_, 256, 0, stream>>>(x, ln1_g, ln1_b, h_bf);
  gemm_bt<<<dim3(24,64), 256, 0, stream>>>(h_bf, wt_attn, b_attn, nullptr, qkv, BT_, 3072, 1024, 0);
  attn_fwd<<<dim3(16,H_,B_), 256, 0, stream>>>(qkv, 3072, qkv+1024, qkv+2048, 3072,
                                               T_, T_, T_, 1, att_out, C_, 0.125f);
  gemm_bt<<<dim3(8,64), 256, 0, stream>>>(att_out, wt_aproj, b_aproj, xcur, xcur, BT_, 1024, 1024, 2);

  // cross-attention
  ln_fwd<<<BT_, 256, 0, stream>>>(xcur, ln1_g, ln1_b, h_bf);
  gemm_bt<<<dim3(8,64), 256, 0, stream>>>(h_bf, wt_q, bq, nullptr, q2, BT_, 1024, 1024, 0);
  gemm_bt<<<dim3(8,16), 256, 0, stream>>>(ximg_bf, wt_k, bk, nullptr, k2, BTI_, 1024, 1024, 0);
  gemm_bt<<<dim3(8,16), 256, 0, stream>>>(ximg_bf, wt_v, bv, nullptr, v2, BTI_, 1024, 1024, 0);
  attn_fwd<<<dim3(16,H_,B_), 256, 0, stream>>>(q2, 1024, k2, v2, 1024,
                                               TI_, TI_, T_, 0, ca, C_, 0.125f);
  gemm_bt<<<dim3(8,64), 256, 0, stream>>>(ca, wt_cproj, bcproj, xcur, xcur, BT_, 1024, 1024, 2);

  // MLP
  ln_fwd<<<BT_, 256, 0, stream>>>(xcur, ln2_g, ln2_b, h_bf);
  gemm_bt<<<dim3(32,64), 256, 0, stream>>>(h_bf, wt_fc, b_fc, nullptr, u_bf, BT_, 4096, 1024, 1);
  gemm_bt<<<dim3(8,64), 256, 0, stream>>>(u_bf, wt_mproj, b_mproj, xcur, (float*)d_out, BT_, 1024, 4096, 2);
}